// Round 21
// baseline (433.065 us; speedup 1.0000x reference)
//
#include <hip/hip_runtime.h>
#include <hip/hip_bf16.h>

// PTV3 attention: sort -> gather+bf16 prepass -> bf16 QKV GEMM -> flash MHA
// (no-max softmax, rolled loop, 2 q-tiles/wave) -> bf16 proj GEMM.
// r21: GEMMs use dbuf LDS + RAW s_barrier + counted vmcnt(8) (T4) so next
// K-tile's global_load_lds stay in flight across the MFMA phase (kills the
// per-iter vmcnt(0) drain that __syncthreads forces).

typedef unsigned long long u64;
typedef unsigned short ushort_t;
typedef __attribute__((ext_vector_type(8))) short short8v;
typedef __attribute__((ext_vector_type(4))) float f32x4;

#define MFMA_BF16 __builtin_amdgcn_mfma_f32_16x16x32_bf16

__device__ __forceinline__ unsigned short f2bf(float f) {
  union { float f; unsigned u; } v; v.f = f;
  return (unsigned short)((v.u + 0x7FFFu + ((v.u >> 16) & 1u)) >> 16);
}

__device__ __forceinline__ unsigned pk2(float a, float b) {
  __hip_bfloat162 h = __float22bfloat162_rn(float2{a, b});
  unsigned u; __builtin_memcpy(&u, &h, 4); return u;
}

// async global->LDS, 16B per lane; LDS dest = wave-uniform base + lane*16
__device__ __forceinline__ void async16(ushort_t* lds, const ushort_t* g) {
  __builtin_amdgcn_global_load_lds(
      (const __attribute__((address_space(1))) unsigned int*)g,
      (__attribute__((address_space(3))) unsigned int*)lds, 16, 0, 0);
}

// ---------------- stable sort of (code, idx) per 16384-group ----------------
// key = (code << 14) | idx -> stable ascending sort.

__global__ __launch_bounds__(512) void sort_chunk(const int* __restrict__ codes,
                                                  u64* __restrict__ keys) {
  __shared__ u64 sk[2048];
  const int base = blockIdx.x * 2048;
  for (int t = threadIdx.x; t < 2048; t += 512) {
    int e = base + t;
    sk[t] = (((u64)(unsigned)codes[e]) << 14) | (u64)(e & 16383);
  }
  __syncthreads();
  for (int k = 2; k <= 2048; k <<= 1) {
    for (int j = k >> 1; j > 0; j >>= 1) {
      for (int t = threadIdx.x; t < 2048; t += 512) {
        int jx = t ^ j;
        if (jx > t) {
          bool up = (((base + t) & 16383 & k) == 0);
          u64 a = sk[t], b = sk[jx];
          if ((a > b) == up) { sk[t] = b; sk[jx] = a; }
        }
      }
      __syncthreads();
    }
  }
  for (int t = threadIdx.x; t < 2048; t += 512) keys[base + t] = sk[t];
}

__global__ __launch_bounds__(256) void sort_gpass(u64* __restrict__ keys, int k, int j) {
  int t = blockIdx.x * 256 + threadIdx.x;
  int jx = t ^ j;
  if (jx > t) {
    bool up = ((t & 16383 & k) == 0);
    u64 a = keys[t], b = keys[jx];
    if ((a > b) == up) { keys[t] = b; keys[jx] = a; }
  }
}

// 4096-span merge finish for level k: sweeps j = min(2048, k/2) .. 1.
__global__ __launch_bounds__(512) void sort_finish(u64* __restrict__ keys, int k) {
  __shared__ u64 sk[4096];
  const int base = blockIdx.x * 4096;
  for (int t = threadIdx.x; t < 4096; t += 512) sk[t] = keys[base + t];
  __syncthreads();
  int j0 = (k >> 1 < 2048) ? (k >> 1) : 2048;
  for (int j = j0; j > 0; j >>= 1) {
    for (int t = threadIdx.x; t < 4096; t += 512) {
      int jx = t ^ j;
      if (jx > t) {
        bool up = (((base + t) & 16383 & k) == 0);
        u64 a = sk[t], b = sk[jx];
        if ((a > b) == up) { sk[t] = b; sk[jx] = a; }
      }
    }
    __syncthreads();
  }
  for (int t = threadIdx.x; t < 4096; t += 512) keys[base + t] = sk[t];
}

// final merge (k=16384): direction uniformly ascending; writes perm directly.
__global__ __launch_bounds__(512) void sort_finish_last(const u64* __restrict__ keys,
                                                        int* __restrict__ perm) {
  __shared__ u64 sk[4096];
  const int base = blockIdx.x * 4096;
  const int g = blockIdx.x >> 2;
  for (int t = threadIdx.x; t < 4096; t += 512) sk[t] = keys[base + t];
  __syncthreads();
  for (int j = 2048; j > 0; j >>= 1) {
    for (int t = threadIdx.x; t < 4096; t += 512) {
      int jx = t ^ j;
      if (jx > t) {
        u64 a = sk[t], b = sk[jx];
        if (a > b) { sk[t] = b; sk[jx] = a; }
      }
    }
    __syncthreads();
  }
  for (int t = threadIdx.x; t < 4096; t += 512)
    perm[base + t] = (g << 14) | (int)(sk[t] & 16383);
}

// ---------------- prepass: Abf[m][k] = bf16(feats[perm[m]][k]) ----------------

__global__ __launch_bounds__(256) void gather_bf16(const float* __restrict__ feats,
    const int* __restrict__ perm, ushort_t* __restrict__ A) {
  int t = blockIdx.x * 256 + threadIdx.x;
  int m = t >> 5;
  int off = (t & 31) << 4;
  const float* src = feats + (size_t)perm[m] * 512 + off;
  float4 a = ((const float4*)src)[0];
  float4 b = ((const float4*)src)[1];
  float4 c = ((const float4*)src)[2];
  float4 d = ((const float4*)src)[3];
  short8v lo = { (short)f2bf(a.x), (short)f2bf(a.y), (short)f2bf(a.z), (short)f2bf(a.w),
                 (short)f2bf(b.x), (short)f2bf(b.y), (short)f2bf(b.z), (short)f2bf(b.w) };
  short8v hi = { (short)f2bf(c.x), (short)f2bf(c.y), (short)f2bf(c.z), (short)f2bf(c.w),
                 (short)f2bf(d.x), (short)f2bf(d.y), (short)f2bf(d.z), (short)f2bf(d.w) };
  ushort_t* dst = A + (size_t)m * 512 + off;
  *(short8v*)(dst) = lo;
  *(short8v*)(dst + 8) = hi;
}

// fused: t < 98304 -> Wqkv (786432 elems / 8), else -> Wproj (262144 / 8)
__global__ __launch_bounds__(256) void convert_both(const float* __restrict__ wq,
    const float* __restrict__ wp, ushort_t* __restrict__ dq, ushort_t* __restrict__ dp) {
  int t = blockIdx.x * 256 + threadIdx.x;
  const float* s;
  ushort_t* d;
  int i;
  if (t < 98304) { s = wq; d = dq; i = t; }
  else           { s = wp; d = dp; i = t - 98304; }
  const float* sp = s + (size_t)i * 8;
  float4 a = ((const float4*)sp)[0];
  float4 b = ((const float4*)sp)[1];
  short8v v = { (short)f2bf(a.x), (short)f2bf(a.y), (short)f2bf(a.z), (short)f2bf(a.w),
                (short)f2bf(b.x), (short)f2bf(b.y), (short)f2bf(b.z), (short)f2bf(b.w) };
  *(short8v*)(d + (size_t)i * 8) = v;
}

// ---------------- QKV GEMM (bf16), T2-swizzled dbuf LDS + counted vmcnt ------

__global__ __launch_bounds__(256) void qkv_gemm(const ushort_t* __restrict__ A,
    const ushort_t* __restrict__ W, const float* __restrict__ bias,
    ushort_t* __restrict__ Q, ushort_t* __restrict__ Ko, ushort_t* __restrict__ Vt)
{
  __shared__ __align__(16) ushort_t la[2][128 * 64];
  __shared__ __align__(16) ushort_t lb[2][128 * 64];
  const int bid = blockIdx.x;                 // 6144 = 12 x 512, XCD-chunked
  const int swz = (bid & 7) * 768 + (bid >> 3);
  const int bx = swz % 12, by = swz / 12;
  const int rowBase = by * 128, colBase = bx * 128;
  const int tid = threadIdx.x, lane = tid & 63, w = tid >> 6;
  const int wr = w >> 1, wc = w & 1;
  const int li = lane & 15, kb = lane >> 4;
  const int lr = lane >> 3;
  const int lcs = (((lane & 7) ^ lr) << 3);   // pre-swizzled source col (elems)
  f32x4 acc[4][4] = {};
  // prologue: stage kt=0 into buf 0 (8 loads/wave)
#pragma unroll
  for (int i = 0; i < 4; ++i) {
    int c = w * 4 + i;
    async16(&la[0][c * 512], A + (size_t)(rowBase + c * 8 + lr) * 512 + lcs);
    async16(&lb[0][c * 512], W + (size_t)(colBase + c * 8 + lr) * 512 + lcs);
  }
#pragma unroll 1
  for (int kt = 0; kt < 8; ++kt) {
    const int cur = kt & 1;
    if (kt < 7) {   // issue next K-tile into the alternate buffer
#pragma unroll
      for (int i = 0; i < 4; ++i) {
        int c = w * 4 + i;
        async16(&la[cur ^ 1][c * 512],
                A + (size_t)(rowBase + c * 8 + lr) * 512 + (kt + 1) * 64 + lcs);
        async16(&lb[cur ^ 1][c * 512],
                W + (size_t)(colBase + c * 8 + lr) * 512 + (kt + 1) * 64 + lcs);
      }
      __builtin_amdgcn_sched_barrier(0);
      asm volatile("s_waitcnt vmcnt(8)" ::: "memory");   // kt's 8 landed; kt+1 in flight
    } else {
      __builtin_amdgcn_sched_barrier(0);
      asm volatile("s_waitcnt vmcnt(0)" ::: "memory");
    }
    __builtin_amdgcn_s_barrier();             // raw: no vmcnt(0) drain
    __builtin_amdgcn_sched_barrier(0);
    const ushort_t* lap = la[cur];
    const ushort_t* lbp = lb[cur];
    short8v af[2][4], bfr[2][4];
#pragma unroll
    for (int kk = 0; kk < 2; ++kk)
#pragma unroll
      for (int t = 0; t < 4; ++t) {
        int sl = ((kk * 4 + kb) ^ (li & 7)) << 3;   // swizzled read slot
        af[kk][t]  = *(const short8v*)(lap + (wr * 64 + t * 16 + li) * 64 + sl);
        bfr[kk][t] = *(const short8v*)(lbp + (wc * 64 + t * 16 + li) * 64 + sl);
      }
#pragma unroll
    for (int kk = 0; kk < 2; ++kk)
#pragma unroll
      for (int i = 0; i < 4; ++i)
#pragma unroll
        for (int j = 0; j < 4; ++j)
          acc[i][j] = MFMA_BF16(af[kk][i], bfr[kk][j], acc[i][j], 0, 0, 0);
    __builtin_amdgcn_sched_barrier(0);
    __builtin_amdgcn_s_barrier();             // all waves done reading buf[cur]
    __builtin_amdgcn_sched_barrier(0);
  }
  const int c0 = colBase + wc * 64;           // wave's first global col
  ushort_t* tw = (w < 2) ? (&la[0][0] + w * 4096) : (&lb[0][0] + (w - 2) * 4096);
  if (c0 >= 1024) {
    // ---- V block: transpose 64x64 subtile via private LDS, store p-contiguous ----
    char* twb = (char*)tw;
#pragma unroll
    for (int j = 0; j < 4; ++j) {
      int dloc = j * 16 + li;
      float bv = bias[c0 + dloc];
#pragma unroll
      for (int i = 0; i < 4; ++i) {
        unsigned u0 = pk2(acc[i][j][0] + bv, acc[i][j][1] + bv);
        unsigned u1 = pk2(acc[i][j][2] + bv, acc[i][j][3] + bv);
        int s = i * 2 + (kb >> 1);
        int byte = dloc * 128 + ((s ^ (dloc & 7)) << 4) + ((kb & 1) << 3);
        *(uint2*)(twb + byte) = make_uint2(u0, u1);
      }
    }
    const int h = (c0 - 1024) >> 6;
    const size_t nh = (size_t)((rowBase >> 9) * 8 + h);
    const int pbase = ((rowBase + wr * 64) & 511) + ((lane & 7) << 3);
    ushort_t* vb = Vt + nh * 32768 + pbase;
#pragma unroll
    for (int ps = 0; ps < 8; ++ps) {
      int dloc = ps * 8 + (lane >> 3);
      int byte = dloc * 128 + ((((lane & 7)) ^ (dloc & 7)) << 4);
      short8v vv = *(const short8v*)(twb + byte);
      *(short8v*)(vb + dloc * 512) = vv;
    }
  } else {
    // ---- Q/K block: transpose 64x64 subtile via private LDS, d-contiguous
    // 16B stores. Q is PRE-SCALED by 0.125*log2e (attn uses exp2f directly).
    const bool isQ = (c0 >> 9) == 0;
    const float qs = isQ ? 0.180336879f : 1.0f;   // 0.125 * log2(e)
    unsigned* twd = (unsigned*)tw;
#pragma unroll
    for (int j = 0; j < 4; ++j) {
      int dl = j * 16 + li;
      float bv = bias[c0 + dl];
#pragma unroll
      for (int i = 0; i < 4; ++i)
#pragma unroll
        for (int r = 0; r < 4; ++r) {
          int p = i * 16 + kb * 4 + r;
          unsigned short hv = f2bf((acc[i][j][r] + bv) * qs);
          int dw = (dl >> 1) ^ (kb << 3);
          *((ushort_t*)(twd + p * 32 + dw) + (dl & 1)) = hv;
        }
    }
    const int hq = (c0 >> 6) & 7;
    const size_t nh = (size_t)((rowBase >> 9) * 8 + hq);
    const int p0w = (rowBase + wr * 64) & 511;
    ushort_t* qb = (isQ ? Q : Ko) + (nh * 512 + p0w) * 64 + ((lane & 7) << 3);
    const int prow = lane >> 3;               // 0..7 within 8-row group
#pragma unroll
    for (int ps = 0; ps < 8; ++ps) {
      int p = ps * 8 + prow;
      int dw0 = ((lane & 7) << 2) ^ ((((p >> 2) & 3)) << 3);
      short8v vv = *(const short8v*)(twd + p * 32 + dw0);
      *(short8v*)(qb + (size_t)p * 64) = vv;
    }
  }
}

// ---------------- flash attention: no-max softmax, ROLLED chunk loop ----------
// Q pre-scaled by 0.125*log2e -> exp2f(S) direct. Both q-tiles' QK^T share one
// kf read pair (halves K LDS reads). l per lane, reduced once in epilogue.
// Rolled loop + sched_barrier(0) prevents spill-inducing cross-chunk pipelining.

#define TILE_EXP(S, LACC, PB) do {                                             \
  _Pragma("unroll")                                                            \
  for (int t = 0; t < 4; ++t)                                                  \
    _Pragma("unroll")                                                          \
    for (int r = 0; r < 4; ++r) S[t][r] = exp2f(S[t][r]);                      \
  float q0 = (S[0][0] + S[0][1]) + (S[0][2] + S[0][3]);                        \
  float q1 = (S[1][0] + S[1][1]) + (S[1][2] + S[1][3]);                        \
  float q2 = (S[2][0] + S[2][1]) + (S[2][2] + S[2][3]);                        \
  float q3 = (S[3][0] + S[3][1]) + (S[3][2] + S[3][3]);                        \
  LACC += (q0 + q1) + (q2 + q3);                                               \
  _Pragma("unroll")                                                            \
  for (int t = 0; t < 4; ++t) {                                                \
    unsigned plo = pk2(S[t][0], S[t][1]);                                      \
    unsigned phi = pk2(S[t][2], S[t][3]);                                      \
    *(uint2*)((char*)(PB) + (((2 * t + (kb >> 1)) << 8) | (li << 4) |          \
                             ((kb & 1) << 3))) = make_uint2(plo, phi);         \
  }                                                                            \
} while (0)

__global__ __launch_bounds__(256, 2) void attn_kernel(const ushort_t* __restrict__ Q,
    const ushort_t* __restrict__ K, const ushort_t* __restrict__ Vt,
    const int* __restrict__ perm, ushort_t* __restrict__ O)
{
  __shared__ __align__(16) ushort_t kbuf[2][64][64];
  __shared__ __align__(16) ushort_t vbuf[2][64][64];
  __shared__ __align__(16) ushort_t pbuf[4][1024];   // per-wave 2KB, slot-major
  const int b = blockIdx.x;                   // 4096 = 128 nh-grp x 4 qc x 8 xcd
  const int qc = (b >> 3) & 3;
  const int nh = ((b >> 5) << 3) | (b & 7);
  const int n = nh >> 3, h = nh & 7;
  const int tid = threadIdx.x, w = tid >> 6, lane = tid & 63;
  const int li = lane & 15, kb = lane >> 4;
  const ushort_t* Qb = Q + (size_t)nh * (512 * 64);
  const ushort_t* Kb = K + (size_t)nh * (512 * 64);
  const ushort_t* Vb = Vt + (size_t)nh * (64 * 512);
  const int p0 = qc * 128 + w * 32;           // tile A rows p0.., tile B p0+16..

  // staging source (pre-swizzled col per rule #21)
  const int srow = lane >> 3;                 // 0..7
  const int ssw = (((lane & 7) ^ srow) << 3);
  const ushort_t* Ksrc = Kb + (size_t)(w * 8 + srow) * 64 + ssw;
  const ushort_t* Vsrc = Vb + (size_t)(w * 8 + srow) * 512 + ssw;

  short8v qa0 = *(const short8v*)(Qb + (size_t)(p0 + li) * 64 + kb * 8);
  short8v qa1 = *(const short8v*)(Qb + (size_t)(p0 + li) * 64 + 32 + kb * 8);
  short8v qb0 = *(const short8v*)(Qb + (size_t)(p0 + 16 + li) * 64 + kb * 8);
  short8v qb1 = *(const short8v*)(Qb + (size_t)(p0 + 16 + li) * 64 + 32 + kb * 8);

  f32x4 oa[4] = {}, ob[4] = {};
  float la_ = 0.f, lb_ = 0.f;                 // per-lane partial row-sums
  ushort_t* pb = &pbuf[w][0];
  const int sl0 = (kb ^ (li & 7)) << 3;         // swizzled K/V read slots
  const int sl1 = ((kb + 4) ^ (li & 7)) << 3;
  const char* prd0 = (const char*)pb + ((kb << 8) | (li << 4));        // slot kb
  const char* prd1 = (const char*)pb + (((kb + 4) << 8) | (li << 4));  // slot kb+4

  // prologue: stage chunk 0 into buf 0
  async16(&kbuf[0][w * 8][0], Ksrc);
  async16(&kbuf[0][w * 8 + 32][0], Ksrc + 2048);
  async16(&vbuf[0][w * 8][0], Vsrc);
  async16(&vbuf[0][w * 8 + 32][0], Vsrc + 16384);
  __syncthreads();

#pragma unroll 1
  for (int ch = 0; ch < 8; ++ch) {
    const int bi = ch & 1;
    if (ch < 7) {   // stage next chunk into the other buffer (drained at barrier)
      async16(&kbuf[bi ^ 1][w * 8][0], Ksrc + (size_t)(ch + 1) * 4096);
      async16(&kbuf[bi ^ 1][w * 8 + 32][0], Ksrc + (size_t)(ch + 1) * 4096 + 2048);
      async16(&vbuf[bi ^ 1][w * 8][0], Vsrc + (ch + 1) * 64);
      async16(&vbuf[bi ^ 1][w * 8 + 32][0], Vsrc + (ch + 1) * 64 + 16384);
    }
    // ---- QK^T both tiles, shared kf reads ----
    f32x4 sA[4], sB[4];
#pragma unroll
    for (int t = 0; t < 4; ++t) {
      short8v kf0 = *(const short8v*)(&kbuf[bi][t * 16 + li][sl0]);
      short8v kf1 = *(const short8v*)(&kbuf[bi][t * 16 + li][sl1]);
      f32x4 zA = {0.f, 0.f, 0.f, 0.f}, zB = {0.f, 0.f, 0.f, 0.f};
      zA = MFMA_BF16(kf0, qa0, zA, 0, 0, 0);
      zB = MFMA_BF16(kf0, qb0, zB, 0, 0, 0);
      zA = MFMA_BF16(kf1, qa1, zA, 0, 0, 0);
      zB = MFMA_BF16(kf1, qb1, zB, 0, 0, 0);
      sA[t] = zA; sB[t] = zB;
    }
    // ---- exp + pack, tile A then tile B (shared pbuf; WAR ordered by lgkmcnt) ----
    short8v pa0, pa1, pb0, pb1;
    TILE_EXP(sA, la_, pb);
    pa0 = *(const short8v*)(prd0);
    pa1 = *(const short8v*)(prd1);
    TILE_EXP(sB, lb_, pb);
    pb0 = *(const short8v*)(prd0);
    pb1 = *(const short8v*)(prd1);
    // ---- PV both tiles (vf shared) ----
    __builtin_amdgcn_s_setprio(1);
#pragma unroll
    for (int dt = 0; dt < 4; ++dt) {
      short8v vf0 = *(const short8v*)(&vbuf[bi][dt * 16 + li][sl0]);
      short8v vf1 = *(const short8v*)(&vbuf[bi][dt * 16 + li][sl1]);
      oa[dt] = MFMA_BF16(pa0, vf0, oa[dt], 0, 0, 0);
      oa[dt] = MFMA_BF16(pa1, vf1, oa[dt], 0, 0, 0);
      ob[dt] = MFMA_BF16(pb0, vf0, ob[dt], 0, 0, 0);
      ob[dt] = MFMA_BF16(pb1, vf1, ob[dt], 0, 0, 0);
    }
    __builtin_amdgcn_s_setprio(0);
    __syncthreads();
    __builtin_amdgcn_sched_barrier(0);        // no cross-chunk motion (r12 spill fix)
  }
  // epilogue: reduce l across kb-lanes once, then write scattered
  la_ += __shfl_xor(la_, 16, 64);
  la_ += __shfl_xor(la_, 32, 64);
  lb_ += __shfl_xor(lb_, 16, 64);
  lb_ += __shfl_xor(lb_, 32, 64);
  {
    float iv = 1.0f / la_;
    float iv4[4];
#pragma unroll
    for (int r = 0; r < 4; ++r) iv4[r] = __shfl(iv, (kb << 2) + r, 16);
    int op[4];
#pragma unroll
    for (int r = 0; r < 4; ++r) op[r] = perm[n * 512 + p0 + kb * 4 + r];
#pragma unroll
    for (int dt = 0; dt < 4; ++dt)
#pragma unroll
      for (int r = 0; r < 4; ++r)
        O[(size_t)op[r] * 512 + h * 64 + dt * 16 + li] = f2bf(oa[dt][r] * iv4[r]);
  }
  {
    float iv = 1.0f / lb_;
    float iv4[4];
#pragma unroll
    for (int r = 0; r < 4; ++r) iv4[r] = __shfl(iv, (kb << 2) + r, 16);
    int op[4];
#pragma unroll
    for (int r = 0; r < 4; ++r) op[r] = perm[n * 512 + p0 + 16 + kb * 4 + r];
#pragma unroll
    for (int dt = 0; dt < 4; ++dt)
#pragma unroll
      for (int r = 0; r < 4; ++r)
        O[(size_t)op[r] * 512 + h * 64 + dt * 16 + li] = f2bf(ob[dt][r] * iv4[r]);
  }
}

// ---------------- proj GEMM (bf16), T2-swizzled dbuf LDS + counted vmcnt -----

__global__ __launch_bounds__(256) void proj_gemm(const ushort_t* __restrict__ A,
    const ushort_t* __restrict__ W, const float* __restrict__ bias,
    float* __restrict__ out)
{
  __shared__ __align__(16) ushort_t la[2][128 * 64];
  __shared__ __align__(16) ushort_t lb[2][128 * 64];
  const int bid = blockIdx.x;                 // 2048 = 4 x 512, XCD-chunked
  const int swz = (bid & 7) * 256 + (bid >> 3);
  const int bx = swz & 3, by = swz >> 2;
  const int rowBase = by * 128, colBase = bx * 128;
  const int tid = threadIdx.x, lane = tid & 63, w = tid >> 6;
  const int wr = w >> 1, wc = w & 1;
  const int li = lane & 15, kb = lane >> 4;
  const int lr = lane >> 3;
  const int lcs = (((lane & 7) ^ lr) << 3);
  f32x4 acc[4][4] = {};
#pragma unroll
  for (int i = 0; i < 4; ++i) {
    int c = w * 4 + i;
    async16(&la[0][c * 512], A + (size_t)(rowBase + c * 8 + lr) * 512 + lcs);
    async16(&lb[0][c * 512], W + (size_t)(colBase + c * 8 + lr) * 512 + lcs);
  }
#pragma unroll 1
  for (int kt = 0; kt < 8; ++kt) {
    const int cur = kt & 1;
    if (kt < 7) {
#pragma unroll
      for (int i = 0; i < 4; ++i) {
        int c = w * 4 + i;
        async16(&la[cur ^ 1][c * 512],
                A + (size_t)(rowBase + c * 8 + lr) * 512 + (kt + 1) * 64 + lcs);
        async16(&lb[cur ^ 1][c * 512],
                W + (size_t)(colBase + c * 8 + lr) * 512 + (kt + 1) * 64 + lcs);
      }
      __builtin_amdgcn_sched_barrier(0);
      asm volatile("s_waitcnt vmcnt(8)" ::: "memory");
    } else {
      __builtin_amdgcn_sched_barrier(0);
      asm volatile("s_waitcnt vmcnt(0)" ::: "memory");
    }
    __builtin_amdgcn_s_barrier();
    __builtin_amdgcn_sched_barrier(0);
    const ushort_t* lap = la[cur];
    const ushort_t* lbp = lb[cur];
    short8v af[2][4], bfr[2][4];
#pragma unroll
    for (int kk = 0; kk < 2; ++kk)
#pragma unroll
      for (int t = 0; t < 4; ++t) {
        int sl = ((kk * 4 + kb) ^ (li & 7)) << 3;
        af[kk][t]  = *(const short8v*)(lap + (wr * 64 + t * 16 + li) * 64 + sl);
        bfr[kk][t] = *(const short8v*)(lbp + (wc * 64 + t * 16 + li) * 64 + sl);
      }
#pragma unroll
    for (int kk = 0; kk < 2; ++kk)
#pragma unroll
      for (int i = 0; i < 4; ++i)
#pragma unroll
        for (int j = 0; j < 4; ++j)
          acc[i][j] = MFMA_BF16(af[kk][i], bfr[kk][j], acc[i][j], 0, 0, 0);
    __builtin_amdgcn_sched_barrier(0);
    __builtin_amdgcn_s_barrier();
    __builtin_amdgcn_sched_barrier(0);
  }
#pragma unroll
  for (int i = 0; i < 4; ++i)
#pragma unroll
    for (int j = 0; j < 4; ++j) {
      int col = colBase + wc * 64 + j * 16 + li;
      float bv = bias[col];
#pragma unroll
      for (int r = 0; r < 4; ++r) {
        int m = rowBase + wr * 64 + i * 16 + kb * 4 + r;
        out[(size_t)m * 512 + col] = acc[i][j][r] + bv;
      }
    }
}

// ---------------- launch ----------------

extern "C" void kernel_launch(void* const* d_in, const int* in_sizes, int n_in,
                              void* d_out, int out_size, void* d_ws, size_t ws_size,
                              hipStream_t stream) {
  (void)in_sizes; (void)n_in; (void)out_size; (void)ws_size;
  const float* feats      = (const float*)d_in[0];
  const int* codes        = (const int*)d_in[1];   // int64 in reference, delivered as int32
  const float* Wqkv       = (const float*)d_in[2];
  const float* bqkv       = (const float*)d_in[3];
  const float* Wproj      = (const float*)d_in[4];
  const float* bproj      = (const float*)d_in[5];
  float* out = (float*)d_out;

  char* ws = (char*)d_ws;
  int* perm = (int*)(ws);
  u64* keys = (u64*)(ws + 262144);
  ushort_t* Abf     = (ushort_t*)(ws + 1048576);                       // 64 MB
  ushort_t* att     = Abf;                                             // reuse
  ushort_t* Wqkvbf  = (ushort_t*)(ws + 1048576 + 67108864);            // 1.5 MB
  ushort_t* Wprojbf = (ushort_t*)(ws + 1048576 + 67108864 + 1572864);  // 0.5 MB
  ushort_t* Qb      = (ushort_t*)(ws + 1048576 + 67108864 + 2097152);
  ushort_t* Kb      = Qb + 33554432ull;
  ushort_t* Vt      = Kb + 33554432ull;

  sort_chunk<<<32, 512, 0, stream>>>(codes, keys);          // chunks of 2048
  sort_finish<<<16, 512, 0, stream>>>(keys, 4096);          // k=4096 fully in LDS
  sort_gpass<<<256, 256, 0, stream>>>(keys, 8192, 4096);
  sort_finish<<<16, 512, 0, stream>>>(keys, 8192);
  sort_gpass<<<256, 256, 0, stream>>>(keys, 16384, 8192);
  sort_gpass<<<256, 256, 0, stream>>>(keys, 16384, 4096);
  sort_finish_last<<<16, 512, 0, stream>>>(keys, perm);

  gather_bf16<<<8192, 256, 0, stream>>>(feats, perm, Abf);
  convert_both<<<512, 256, 0, stream>>>(Wqkv, Wproj, Wqkvbf, Wprojbf);

  qkv_gemm<<<6144, 256, 0, stream>>>(Abf, Wqkvbf, bqkv, Qb, Kb, Vt);
  attn_kernel<<<4096, 256, 0, stream>>>(Qb, Kb, Vt, perm, att);
  proj_gemm<<<2048, 256, 0, stream>>>(att, Wprojbf, bproj, out);
}

// Round 22
// 397.497 us; speedup vs baseline: 1.0895x; 1.0895x over previous
//
#include <hip/hip_runtime.h>
#include <hip/hip_bf16.h>

// PTV3 attention: sort -> gather+bf16 prepass -> bf16 QKV GEMM -> flash MHA
// (no-max softmax, rolled loop, 2 q-tiles/wave) -> bf16 proj GEMM.
// r22: revert to r20 best (403 us). r21's dbuf+counted-vmcnt regressed qkv
// 136->170 us: 64KB LDS halved blocks/CU (occ 29->20), killing the TLP that
// covered intra-phase latency — at 32KB tiles the 2-barrier m97 structure
// with __syncthreads + 5 blocks/CU is the local optimum.

typedef unsigned long long u64;
typedef unsigned short ushort_t;
typedef __attribute__((ext_vector_type(8))) short short8v;
typedef __attribute__((ext_vector_type(4))) float f32x4;

#define MFMA_BF16 __builtin_amdgcn_mfma_f32_16x16x32_bf16

__device__ __forceinline__ unsigned short f2bf(float f) {
  union { float f; unsigned u; } v; v.f = f;
  return (unsigned short)((v.u + 0x7FFFu + ((v.u >> 16) & 1u)) >> 16);
}

__device__ __forceinline__ unsigned pk2(float a, float b) {
  __hip_bfloat162 h = __float22bfloat162_rn(float2{a, b});
  unsigned u; __builtin_memcpy(&u, &h, 4); return u;
}

// async global->LDS, 16B per lane; LDS dest = wave-uniform base + lane*16
__device__ __forceinline__ void async16(ushort_t* lds, const ushort_t* g) {
  __builtin_amdgcn_global_load_lds(
      (const __attribute__((address_space(1))) unsigned int*)g,
      (__attribute__((address_space(3))) unsigned int*)lds, 16, 0, 0);
}

// ---------------- stable sort of (code, idx) per 16384-group ----------------
// key = (code << 14) | idx -> stable ascending sort.

__global__ __launch_bounds__(512) void sort_chunk(const int* __restrict__ codes,
                                                  u64* __restrict__ keys) {
  __shared__ u64 sk[2048];
  const int base = blockIdx.x * 2048;
  for (int t = threadIdx.x; t < 2048; t += 512) {
    int e = base + t;
    sk[t] = (((u64)(unsigned)codes[e]) << 14) | (u64)(e & 16383);
  }
  __syncthreads();
  for (int k = 2; k <= 2048; k <<= 1) {
    for (int j = k >> 1; j > 0; j >>= 1) {
      for (int t = threadIdx.x; t < 2048; t += 512) {
        int jx = t ^ j;
        if (jx > t) {
          bool up = (((base + t) & 16383 & k) == 0);
          u64 a = sk[t], b = sk[jx];
          if ((a > b) == up) { sk[t] = b; sk[jx] = a; }
        }
      }
      __syncthreads();
    }
  }
  for (int t = threadIdx.x; t < 2048; t += 512) keys[base + t] = sk[t];
}

__global__ __launch_bounds__(256) void sort_gpass(u64* __restrict__ keys, int k, int j) {
  int t = blockIdx.x * 256 + threadIdx.x;
  int jx = t ^ j;
  if (jx > t) {
    bool up = ((t & 16383 & k) == 0);
    u64 a = keys[t], b = keys[jx];
    if ((a > b) == up) { keys[t] = b; keys[jx] = a; }
  }
}

// 4096-span merge finish for level k: sweeps j = min(2048, k/2) .. 1.
__global__ __launch_bounds__(512) void sort_finish(u64* __restrict__ keys, int k) {
  __shared__ u64 sk[4096];
  const int base = blockIdx.x * 4096;
  for (int t = threadIdx.x; t < 4096; t += 512) sk[t] = keys[base + t];
  __syncthreads();
  int j0 = (k >> 1 < 2048) ? (k >> 1) : 2048;
  for (int j = j0; j > 0; j >>= 1) {
    for (int t = threadIdx.x; t < 4096; t += 512) {
      int jx = t ^ j;
      if (jx > t) {
        bool up = (((base + t) & 16383 & k) == 0);
        u64 a = sk[t], b = sk[jx];
        if ((a > b) == up) { sk[t] = b; sk[jx] = a; }
      }
    }
    __syncthreads();
  }
  for (int t = threadIdx.x; t < 4096; t += 512) keys[base + t] = sk[t];
}

// final merge (k=16384): direction uniformly ascending; writes perm directly.
__global__ __launch_bounds__(512) void sort_finish_last(const u64* __restrict__ keys,
                                                        int* __restrict__ perm) {
  __shared__ u64 sk[4096];
  const int base = blockIdx.x * 4096;
  const int g = blockIdx.x >> 2;
  for (int t = threadIdx.x; t < 4096; t += 512) sk[t] = keys[base + t];
  __syncthreads();
  for (int j = 2048; j > 0; j >>= 1) {
    for (int t = threadIdx.x; t < 4096; t += 512) {
      int jx = t ^ j;
      if (jx > t) {
        u64 a = sk[t], b = sk[jx];
        if (a > b) { sk[t] = b; sk[jx] = a; }
      }
    }
    __syncthreads();
  }
  for (int t = threadIdx.x; t < 4096; t += 512)
    perm[base + t] = (g << 14) | (int)(sk[t] & 16383);
}

// ---------------- prepass: Abf[m][k] = bf16(feats[perm[m]][k]) ----------------

__global__ __launch_bounds__(256) void gather_bf16(const float* __restrict__ feats,
    const int* __restrict__ perm, ushort_t* __restrict__ A) {
  int t = blockIdx.x * 256 + threadIdx.x;
  int m = t >> 5;
  int off = (t & 31) << 4;
  const float* src = feats + (size_t)perm[m] * 512 + off;
  float4 a = ((const float4*)src)[0];
  float4 b = ((const float4*)src)[1];
  float4 c = ((const float4*)src)[2];
  float4 d = ((const float4*)src)[3];
  short8v lo = { (short)f2bf(a.x), (short)f2bf(a.y), (short)f2bf(a.z), (short)f2bf(a.w),
                 (short)f2bf(b.x), (short)f2bf(b.y), (short)f2bf(b.z), (short)f2bf(b.w) };
  short8v hi = { (short)f2bf(c.x), (short)f2bf(c.y), (short)f2bf(c.z), (short)f2bf(c.w),
                 (short)f2bf(d.x), (short)f2bf(d.y), (short)f2bf(d.z), (short)f2bf(d.w) };
  ushort_t* dst = A + (size_t)m * 512 + off;
  *(short8v*)(dst) = lo;
  *(short8v*)(dst + 8) = hi;
}

// fused: t < 98304 -> Wqkv (786432 elems / 8), else -> Wproj (262144 / 8)
__global__ __launch_bounds__(256) void convert_both(const float* __restrict__ wq,
    const float* __restrict__ wp, ushort_t* __restrict__ dq, ushort_t* __restrict__ dp) {
  int t = blockIdx.x * 256 + threadIdx.x;
  const float* s;
  ushort_t* d;
  int i;
  if (t < 98304) { s = wq; d = dq; i = t; }
  else           { s = wp; d = dp; i = t - 98304; }
  const float* sp = s + (size_t)i * 8;
  float4 a = ((const float4*)sp)[0];
  float4 b = ((const float4*)sp)[1];
  short8v v = { (short)f2bf(a.x), (short)f2bf(a.y), (short)f2bf(a.z), (short)f2bf(a.w),
                (short)f2bf(b.x), (short)f2bf(b.y), (short)f2bf(b.z), (short)f2bf(b.w) };
  *(short8v*)(d + (size_t)i * 8) = v;
}

// ---------------- QKV GEMM (bf16), T2-swizzled LDS ----------------

__global__ __launch_bounds__(256) void qkv_gemm(const ushort_t* __restrict__ A,
    const ushort_t* __restrict__ W, const float* __restrict__ bias,
    ushort_t* __restrict__ Q, ushort_t* __restrict__ Ko, ushort_t* __restrict__ Vt)
{
  __shared__ __align__(16) ushort_t la[128 * 64];
  __shared__ __align__(16) ushort_t lb[128 * 64];
  const int bid = blockIdx.x;                 // 6144 = 12 x 512, XCD-chunked
  const int swz = (bid & 7) * 768 + (bid >> 3);
  const int bx = swz % 12, by = swz / 12;
  const int rowBase = by * 128, colBase = bx * 128;
  const int tid = threadIdx.x, lane = tid & 63, w = tid >> 6;
  const int wr = w >> 1, wc = w & 1;
  const int li = lane & 15, kb = lane >> 4;
  const int lr = lane >> 3;
  const int lcs = (((lane & 7) ^ lr) << 3);   // pre-swizzled source col (elems)
  f32x4 acc[4][4] = {};
  for (int kt = 0; kt < 8; ++kt) {
#pragma unroll
    for (int i = 0; i < 4; ++i) {
      int c = w * 4 + i;
      async16(la + c * 512, A + (size_t)(rowBase + c * 8 + lr) * 512 + kt * 64 + lcs);
      async16(lb + c * 512, W + (size_t)(colBase + c * 8 + lr) * 512 + kt * 64 + lcs);
    }
    __syncthreads();
    short8v af[2][4], bfr[2][4];
#pragma unroll
    for (int kk = 0; kk < 2; ++kk)
#pragma unroll
      for (int t = 0; t < 4; ++t) {
        int sl = ((kk * 4 + kb) ^ (li & 7)) << 3;   // swizzled read slot
        af[kk][t]  = *(const short8v*)(la + (wr * 64 + t * 16 + li) * 64 + sl);
        bfr[kk][t] = *(const short8v*)(lb + (wc * 64 + t * 16 + li) * 64 + sl);
      }
#pragma unroll
    for (int kk = 0; kk < 2; ++kk)
#pragma unroll
      for (int i = 0; i < 4; ++i)
#pragma unroll
        for (int j = 0; j < 4; ++j)
          acc[i][j] = MFMA_BF16(af[kk][i], bfr[kk][j], acc[i][j], 0, 0, 0);
    __syncthreads();
  }
  const int c0 = colBase + wc * 64;           // wave's first global col
  ushort_t* tw = (w < 2) ? (la + w * 4096) : (lb + (w - 2) * 4096);
  if (c0 >= 1024) {
    // ---- V block: transpose 64x64 subtile via private LDS, store p-contiguous ----
    char* twb = (char*)tw;
#pragma unroll
    for (int j = 0; j < 4; ++j) {
      int dloc = j * 16 + li;
      float bv = bias[c0 + dloc];
#pragma unroll
      for (int i = 0; i < 4; ++i) {
        unsigned u0 = pk2(acc[i][j][0] + bv, acc[i][j][1] + bv);
        unsigned u1 = pk2(acc[i][j][2] + bv, acc[i][j][3] + bv);
        int s = i * 2 + (kb >> 1);
        int byte = dloc * 128 + ((s ^ (dloc & 7)) << 4) + ((kb & 1) << 3);
        *(uint2*)(twb + byte) = make_uint2(u0, u1);
      }
    }
    const int h = (c0 - 1024) >> 6;
    const size_t nh = (size_t)((rowBase >> 9) * 8 + h);
    const int pbase = ((rowBase + wr * 64) & 511) + ((lane & 7) << 3);
    ushort_t* vb = Vt + nh * 32768 + pbase;
#pragma unroll
    for (int ps = 0; ps < 8; ++ps) {
      int dloc = ps * 8 + (lane >> 3);
      int byte = dloc * 128 + ((((lane & 7)) ^ (dloc & 7)) << 4);
      short8v vv = *(const short8v*)(twb + byte);
      *(short8v*)(vb + dloc * 512) = vv;
    }
  } else {
    // ---- Q/K block: transpose 64x64 subtile via private LDS, d-contiguous
    // 16B stores. Q is PRE-SCALED by 0.125*log2e (attn uses exp2f directly).
    const bool isQ = (c0 >> 9) == 0;
    const float qs = isQ ? 0.180336879f : 1.0f;   // 0.125 * log2(e)
    unsigned* twd = (unsigned*)tw;
#pragma unroll
    for (int j = 0; j < 4; ++j) {
      int dl = j * 16 + li;
      float bv = bias[c0 + dl];
#pragma unroll
      for (int i = 0; i < 4; ++i)
#pragma unroll
        for (int r = 0; r < 4; ++r) {
          int p = i * 16 + kb * 4 + r;
          unsigned short hv = f2bf((acc[i][j][r] + bv) * qs);
          int dw = (dl >> 1) ^ (kb << 3);
          *((ushort_t*)(twd + p * 32 + dw) + (dl & 1)) = hv;
        }
    }
    const int hq = (c0 >> 6) & 7;
    const size_t nh = (size_t)((rowBase >> 9) * 8 + hq);
    const int p0w = (rowBase + wr * 64) & 511;
    ushort_t* qb = (isQ ? Q : Ko) + (nh * 512 + p0w) * 64 + ((lane & 7) << 3);
    const int prow = lane >> 3;               // 0..7 within 8-row group
#pragma unroll
    for (int ps = 0; ps < 8; ++ps) {
      int p = ps * 8 + prow;
      int dw0 = ((lane & 7) << 2) ^ ((((p >> 2) & 3)) << 3);
      short8v vv = *(const short8v*)(twd + p * 32 + dw0);
      *(short8v*)(qb + (size_t)p * 64) = vv;
    }
  }
}

// ---------------- flash attention: no-max softmax, ROLLED chunk loop ----------
// Q pre-scaled by 0.125*log2e -> exp2f(S) direct. Both q-tiles' QK^T share one
// kf read pair (halves K LDS reads). l per lane, reduced once in epilogue.
// Rolled loop + sched_barrier(0) prevents spill-inducing cross-chunk pipelining.

#define TILE_EXP(S, LACC, PB) do {                                             \
  _Pragma("unroll")                                                            \
  for (int t = 0; t < 4; ++t)                                                  \
    _Pragma("unroll")                                                          \
    for (int r = 0; r < 4; ++r) S[t][r] = exp2f(S[t][r]);                      \
  float q0 = (S[0][0] + S[0][1]) + (S[0][2] + S[0][3]);                        \
  float q1 = (S[1][0] + S[1][1]) + (S[1][2] + S[1][3]);                        \
  float q2 = (S[2][0] + S[2][1]) + (S[2][2] + S[2][3]);                        \
  float q3 = (S[3][0] + S[3][1]) + (S[3][2] + S[3][3]);                        \
  LACC += (q0 + q1) + (q2 + q3);                                               \
  _Pragma("unroll")                                                            \
  for (int t = 0; t < 4; ++t) {                                                \
    unsigned plo = pk2(S[t][0], S[t][1]);                                      \
    unsigned phi = pk2(S[t][2], S[t][3]);                                      \
    *(uint2*)((char*)(PB) + (((2 * t + (kb >> 1)) << 8) | (li << 4) |          \
                             ((kb & 1) << 3))) = make_uint2(plo, phi);         \
  }                                                                            \
} while (0)

__global__ __launch_bounds__(256, 2) void attn_kernel(const ushort_t* __restrict__ Q,
    const ushort_t* __restrict__ K, const ushort_t* __restrict__ Vt,
    const int* __restrict__ perm, ushort_t* __restrict__ O)
{
  __shared__ __align__(16) ushort_t kbuf[2][64][64];
  __shared__ __align__(16) ushort_t vbuf[2][64][64];
  __shared__ __align__(16) ushort_t pbuf[4][1024];   // per-wave 2KB, slot-major
  const int b = blockIdx.x;                   // 4096 = 128 nh-grp x 4 qc x 8 xcd
  const int qc = (b >> 3) & 3;
  const int nh = ((b >> 5) << 3) | (b & 7);
  const int n = nh >> 3, h = nh & 7;
  const int tid = threadIdx.x, w = tid >> 6, lane = tid & 63;
  const int li = lane & 15, kb = lane >> 4;
  const ushort_t* Qb = Q + (size_t)nh * (512 * 64);
  const ushort_t* Kb = K + (size_t)nh * (512 * 64);
  const ushort_t* Vb = Vt + (size_t)nh * (64 * 512);
  const int p0 = qc * 128 + w * 32;           // tile A rows p0.., tile B p0+16..

  // staging source (pre-swizzled col per rule #21)
  const int srow = lane >> 3;                 // 0..7
  const int ssw = (((lane & 7) ^ srow) << 3);
  const ushort_t* Ksrc = Kb + (size_t)(w * 8 + srow) * 64 + ssw;
  const ushort_t* Vsrc = Vb + (size_t)(w * 8 + srow) * 512 + ssw;

  short8v qa0 = *(const short8v*)(Qb + (size_t)(p0 + li) * 64 + kb * 8);
  short8v qa1 = *(const short8v*)(Qb + (size_t)(p0 + li) * 64 + 32 + kb * 8);
  short8v qb0 = *(const short8v*)(Qb + (size_t)(p0 + 16 + li) * 64 + kb * 8);
  short8v qb1 = *(const short8v*)(Qb + (size_t)(p0 + 16 + li) * 64 + 32 + kb * 8);

  f32x4 oa[4] = {}, ob[4] = {};
  float la_ = 0.f, lb_ = 0.f;                 // per-lane partial row-sums
  ushort_t* pb = &pbuf[w][0];
  const int sl0 = (kb ^ (li & 7)) << 3;         // swizzled K/V read slots
  const int sl1 = ((kb + 4) ^ (li & 7)) << 3;
  const char* prd0 = (const char*)pb + ((kb << 8) | (li << 4));        // slot kb
  const char* prd1 = (const char*)pb + (((kb + 4) << 8) | (li << 4));  // slot kb+4

  // prologue: stage chunk 0 into buf 0
  async16(&kbuf[0][w * 8][0], Ksrc);
  async16(&kbuf[0][w * 8 + 32][0], Ksrc + 2048);
  async16(&vbuf[0][w * 8][0], Vsrc);
  async16(&vbuf[0][w * 8 + 32][0], Vsrc + 16384);
  __syncthreads();

#pragma unroll 1
  for (int ch = 0; ch < 8; ++ch) {
    const int bi = ch & 1;
    if (ch < 7) {   // stage next chunk into the other buffer (drained at barrier)
      async16(&kbuf[bi ^ 1][w * 8][0], Ksrc + (size_t)(ch + 1) * 4096);
      async16(&kbuf[bi ^ 1][w * 8 + 32][0], Ksrc + (size_t)(ch + 1) * 4096 + 2048);
      async16(&vbuf[bi ^ 1][w * 8][0], Vsrc + (ch + 1) * 64);
      async16(&vbuf[bi ^ 1][w * 8 + 32][0], Vsrc + (ch + 1) * 64 + 16384);
    }
    // ---- QK^T both tiles, shared kf reads ----
    f32x4 sA[4], sB[4];
#pragma unroll
    for (int t = 0; t < 4; ++t) {
      short8v kf0 = *(const short8v*)(&kbuf[bi][t * 16 + li][sl0]);
      short8v kf1 = *(const short8v*)(&kbuf[bi][t * 16 + li][sl1]);
      f32x4 zA = {0.f, 0.f, 0.f, 0.f}, zB = {0.f, 0.f, 0.f, 0.f};
      zA = MFMA_BF16(kf0, qa0, zA, 0, 0, 0);
      zB = MFMA_BF16(kf0, qb0, zB, 0, 0, 0);
      zA = MFMA_BF16(kf1, qa1, zA, 0, 0, 0);
      zB = MFMA_BF16(kf1, qb1, zB, 0, 0, 0);
      sA[t] = zA; sB[t] = zB;
    }
    // ---- exp + pack, tile A then tile B (shared pbuf; WAR ordered by lgkmcnt) ----
    short8v pa0, pa1, pb0, pb1;
    TILE_EXP(sA, la_, pb);
    pa0 = *(const short8v*)(prd0);
    pa1 = *(const short8v*)(prd1);
    TILE_EXP(sB, lb_, pb);
    pb0 = *(const short8v*)(prd0);
    pb1 = *(const short8v*)(prd1);
    // ---- PV both tiles (vf shared) ----
    __builtin_amdgcn_s_setprio(1);
#pragma unroll
    for (int dt = 0; dt < 4; ++dt) {
      short8v vf0 = *(const short8v*)(&vbuf[bi][dt * 16 + li][sl0]);
      short8v vf1 = *(const short8v*)(&vbuf[bi][dt * 16 + li][sl1]);
      oa[dt] = MFMA_BF16(pa0, vf0, oa[dt], 0, 0, 0);
      oa[dt] = MFMA_BF16(pa1, vf1, oa[dt], 0, 0, 0);
      ob[dt] = MFMA_BF16(pb0, vf0, ob[dt], 0, 0, 0);
      ob[dt] = MFMA_BF16(pb1, vf1, ob[dt], 0, 0, 0);
    }
    __builtin_amdgcn_s_setprio(0);
    __syncthreads();
    __builtin_amdgcn_sched_barrier(0);        // no cross-chunk motion (r12 spill fix)
  }
  // epilogue: reduce l across kb-lanes once, then write scattered
  la_ += __shfl_xor(la_, 16, 64);
  la_ += __shfl_xor(la_, 32, 64);
  lb_ += __shfl_xor(lb_, 16, 64);
  lb_ += __shfl_xor(lb_, 32, 64);
  {
    float iv = 1.0f / la_;
    float iv4[4];
#pragma unroll
    for (int r = 0; r < 4; ++r) iv4[r] = __shfl(iv, (kb << 2) + r, 16);
    int op[4];
#pragma unroll
    for (int r = 0; r < 4; ++r) op[r] = perm[n * 512 + p0 + kb * 4 + r];
#pragma unroll
    for (int dt = 0; dt < 4; ++dt)
#pragma unroll
      for (int r = 0; r < 4; ++r)
        O[(size_t)op[r] * 512 + h * 64 + dt * 16 + li] = f2bf(oa[dt][r] * iv4[r]);
  }
  {
    float iv = 1.0f / lb_;
    float iv4[4];
#pragma unroll
    for (int r = 0; r < 4; ++r) iv4[r] = __shfl(iv, (kb << 2) + r, 16);
    int op[4];
#pragma unroll
    for (int r = 0; r < 4; ++r) op[r] = perm[n * 512 + p0 + 16 + kb * 4 + r];
#pragma unroll
    for (int dt = 0; dt < 4; ++dt)
#pragma unroll
      for (int r = 0; r < 4; ++r)
        O[(size_t)op[r] * 512 + h * 64 + dt * 16 + li] = f2bf(ob[dt][r] * iv4[r]);
  }
}

// ---------------- proj GEMM (bf16), T2-swizzled LDS ----------------

__global__ __launch_bounds__(256) void proj_gemm(const ushort_t* __restrict__ A,
    const ushort_t* __restrict__ W, const float* __restrict__ bias,
    float* __restrict__ out)
{
  __shared__ __align__(16) ushort_t la[128 * 64];
  __shared__ __align__(16) ushort_t lb[128 * 64];
  const int bid = blockIdx.x;                 // 2048 = 4 x 512, XCD-chunked
  const int swz = (bid & 7) * 256 + (bid >> 3);
  const int bx = swz & 3, by = swz >> 2;
  const int rowBase = by * 128, colBase = bx * 128;
  const int tid = threadIdx.x, lane = tid & 63, w = tid >> 6;
  const int wr = w >> 1, wc = w & 1;
  const int li = lane & 15, kb = lane >> 4;
  const int lr = lane >> 3;
  const int lcs = (((lane & 7) ^ lr) << 3);
  f32x4 acc[4][4] = {};
  for (int kt = 0; kt < 8; ++kt) {
#pragma unroll
    for (int i = 0; i < 4; ++i) {
      int c = w * 4 + i;
      async16(la + c * 512, A + (size_t)(rowBase + c * 8 + lr) * 512 + kt * 64 + lcs);
      async16(lb + c * 512, W + (size_t)(colBase + c * 8 + lr) * 512 + kt * 64 + lcs);
    }
    __syncthreads();
    short8v af[2][4], bfr[2][4];
#pragma unroll
    for (int kk = 0; kk < 2; ++kk)
#pragma unroll
      for (int t = 0; t < 4; ++t) {
        int sl = ((kk * 4 + kb) ^ (li & 7)) << 3;
        af[kk][t]  = *(const short8v*)(la + (wr * 64 + t * 16 + li) * 64 + sl);
        bfr[kk][t] = *(const short8v*)(lb + (wc * 64 + t * 16 + li) * 64 + sl);
      }
#pragma unroll
    for (int kk = 0; kk < 2; ++kk)
#pragma unroll
      for (int i = 0; i < 4; ++i)
#pragma unroll
        for (int j = 0; j < 4; ++j)
          acc[i][j] = MFMA_BF16(af[kk][i], bfr[kk][j], acc[i][j], 0, 0, 0);
    __syncthreads();
  }
#pragma unroll
  for (int i = 0; i < 4; ++i)
#pragma unroll
    for (int j = 0; j < 4; ++j) {
      int col = colBase + wc * 64 + j * 16 + li;
      float bv = bias[col];
#pragma unroll
      for (int r = 0; r < 4; ++r) {
        int m = rowBase + wr * 64 + i * 16 + kb * 4 + r;
        out[(size_t)m * 512 + col] = acc[i][j][r] + bv;
      }
    }
}

// ---------------- launch ----------------

extern "C" void kernel_launch(void* const* d_in, const int* in_sizes, int n_in,
                              void* d_out, int out_size, void* d_ws, size_t ws_size,
                              hipStream_t stream) {
  (void)in_sizes; (void)n_in; (void)out_size; (void)ws_size;
  const float* feats      = (const float*)d_in[0];
  const int* codes        = (const int*)d_in[1];   // int64 in reference, delivered as int32
  const float* Wqkv       = (const float*)d_in[2];
  const float* bqkv       = (const float*)d_in[3];
  const float* Wproj      = (const float*)d_in[4];
  const float* bproj      = (const float*)d_in[5];
  float* out = (float*)d_out;

  char* ws = (char*)d_ws;
  int* perm = (int*)(ws);
  u64* keys = (u64*)(ws + 262144);
  ushort_t* Abf     = (ushort_t*)(ws + 1048576);                       // 64 MB
  ushort_t* att     = Abf;                                             // reuse
  ushort_t* Wqkvbf  = (ushort_t*)(ws + 1048576 + 67108864);            // 1.5 MB
  ushort_t* Wprojbf = (ushort_t*)(ws + 1048576 + 67108864 + 1572864);  // 0.5 MB
  ushort_t* Qb      = (ushort_t*)(ws + 1048576 + 67108864 + 2097152);
  ushort_t* Kb      = Qb + 33554432ull;
  ushort_t* Vt      = Kb + 33554432ull;

  sort_chunk<<<32, 512, 0, stream>>>(codes, keys);          // chunks of 2048
  sort_finish<<<16, 512, 0, stream>>>(keys, 4096);          // k=4096 fully in LDS
  sort_gpass<<<256, 256, 0, stream>>>(keys, 8192, 4096);
  sort_finish<<<16, 512, 0, stream>>>(keys, 8192);
  sort_gpass<<<256, 256, 0, stream>>>(keys, 16384, 8192);
  sort_gpass<<<256, 256, 0, stream>>>(keys, 16384, 4096);
  sort_finish_last<<<16, 512, 0, stream>>>(keys, perm);

  gather_bf16<<<8192, 256, 0, stream>>>(feats, perm, Abf);
  convert_both<<<512, 256, 0, stream>>>(Wqkv, Wproj, Wqkvbf, Wprojbf);

  qkv_gemm<<<6144, 256, 0, stream>>>(Abf, Wqkvbf, bqkv, Qb, Kb, Vt);
  attn_kernel<<<4096, 256, 0, stream>>>(Qb, Kb, Vt, perm, att);
  proj_gemm<<<2048, 256, 0, stream>>>(att, Wprojbf, bproj, out);
}